// Round 20
// baseline (676.236 us; speedup 1.0000x reference)
//
#include <hip/hip_runtime.h>
#include <hip/hip_bf16.h>

typedef unsigned short u16;
typedef unsigned int u32;
typedef __attribute__((ext_vector_type(2))) unsigned int u32x2;
typedef __attribute__((ext_vector_type(4))) unsigned int u32x4;
typedef __attribute__((ext_vector_type(4))) float f32x4;
typedef __attribute__((ext_vector_type(8))) short bf16x8;    // 8 bf16 (4 VGPRs)
typedef __attribute__((ext_vector_type(16))) float f32x16;   // 32x32 MFMA C/D

typedef __attribute__((address_space(1))) const void as1_cvoid;
typedef __attribute__((address_space(3))) void as3_void;

__device__ __forceinline__ u32 cvtpk(float lo, float hi) {   // v_cvt_pk_bf16_f32
    __hip_bfloat162 h = __float22bfloat162_rn(make_float2(lo, hi));
    u32 r; __builtin_memcpy(&r, &h, 4);
    return r;
}
__device__ __forceinline__ int crow(int r, int hl) { return (r & 3) + 8 * (r >> 2) + 4 * hl; }

#define NROW 4096
#define CK 64
#define CV 128
#define TILE_U16 24576          // one 128-row tile image: K 16KB + V^T 32KB = 48KB
#define WS_NEEDED (8u * 32u * 49152u)   // 12,582,912 B
// K tile [128 j][64 c] bf16, 128B rows:
#define SWK(R, o) ((((R) << 7) + (o)) ^ (((R) & 7) << 4))
// V^T tile [128 v][128 j] bf16, 256B rows:
#define SWVG(R) ((((R) >> 3) & 15) ^ (((R) & 7) << 1))
#define SWV(R, o) ((((R) << 8) + (o)) ^ (SWVG(R) << 4))

// ===========================================================================
// Prepass: per-(batch,tile) 48KB LDS images in d_ws (K swizzled + V^T swizzled);
// linear DMA of an image reproduces the exact swizzled LDS layout (m173).
// ===========================================================================
__global__ __launch_bounds__(512, 2) void prep_k(const float* __restrict__ Kg,
                                                 const float* __restrict__ Vg,
                                                 u16* __restrict__ ws) {
    int bid = blockIdx.x;
    int b = bid >> 5, jt = bid & 31;
    int t = threadIdx.x;
    int jK = t >> 2, kc4 = t & 3;
    int vg = t & 15, jgrp = t >> 4;
    const float* Kp = Kg + ((size_t)b * NROW + jt * 128) * CK;
    const float* Vp = Vg + ((size_t)b * NROW + jt * 128) * CV;
    u16* img = ws + (size_t)(b * 32 + jt) * TILE_U16;

    {   // K part
        const float* kp = Kp + (size_t)jK * CK + kc4 * 16;
        f32x4 a0 = *(const f32x4*)kp,       a1 = *(const f32x4*)(kp + 4);
        f32x4 a2 = *(const f32x4*)(kp + 8), a3 = *(const f32x4*)(kp + 12);
        u32x4 kk0, kk1;
        kk0[0] = cvtpk(a0[0], a0[1]); kk0[1] = cvtpk(a0[2], a0[3]);
        kk0[2] = cvtpk(a1[0], a1[1]); kk0[3] = cvtpk(a1[2], a1[3]);
        kk1[0] = cvtpk(a2[0], a2[1]); kk1[1] = cvtpk(a2[2], a2[3]);
        kk1[2] = cvtpk(a3[0], a3[1]); kk1[3] = cvtpk(a3[2], a3[3]);
        *(u32x4*)&img[SWK(jK, kc4 * 32) >> 1]      = kk0;
        *(u32x4*)&img[SWK(jK, kc4 * 32 + 16) >> 1] = kk1;
    }
    {   // V part (transpose 4 j-rows x 8 v-cols)
        const float* vp = Vp + (size_t)(jgrp * 4) * CV + vg * 8;
        f32x4 va0 = *(const f32x4*)vp,            vb0 = *(const f32x4*)(vp + 4);
        f32x4 va1 = *(const f32x4*)(vp + CV),     vb1 = *(const f32x4*)(vp + CV + 4);
        f32x4 va2 = *(const f32x4*)(vp + 2 * CV), vb2 = *(const f32x4*)(vp + 2 * CV + 4);
        f32x4 va3 = *(const f32x4*)(vp + 3 * CV), vb3 = *(const f32x4*)(vp + 3 * CV + 4);
#pragma unroll
        for (int x = 0; x < 4; x++) {
            u32x2 vv;
            vv[0] = cvtpk(va0[x], va1[x]); vv[1] = cvtpk(va2[x], va3[x]);
            *(u32x2*)&img[8192 + (SWV(vg * 8 + x, jgrp * 8) >> 1)] = vv;
            vv[0] = cvtpk(vb0[x], vb1[x]); vv[1] = cvtpk(vb2[x], vb3[x]);
            *(u32x2*)&img[8192 + (SWV(vg * 8 + 4 + x, jgrp * 8) >> 1)] = vv;
        }
    }
}

// ===========================================================================
// Main: 256 blocks x 512 thr (8 waves), 1 block/CU. 33 equal rounds/block
// (phase A: unit u, u+1 rounds; phase B: unit 31-u, 32-u rounds).
// NEW vs r13: each wave owns TWO adjacent q-tiles (T0 = 4*u_phase + 2*qs2,
// T1 = T0+1) sharing the SAME K/V fragments: 12 ds_reads feed 24 MFMAs, and
// the second tile's QK/softmax is independent register-work that fills the
// first tile's latency stalls (issue slots were only ~18% occupied).
// acc doubled to 8 x f32x16; phase-B Q reloaded at the switch (reg budget).
// ===========================================================================
__global__ __launch_bounds__(512, 1) void attn_m(const float* __restrict__ Qg,
                                                 const u16* __restrict__ ws,
                                                 float* __restrict__ O) {
    __shared__ __align__(16) u16 smem[2 * TILE_U16 + 16512];

    int bid = blockIdx.x;
    int bb = bid & 7;
    int u  = bid >> 3;                  // 0..31
    int t  = threadIdx.x;
    int w  = t >> 6;
    int lane = t & 63;
    int ql = lane & 31, hl = lane >> 5;
    int qs2 = w >> 2;                   // q-tile-pair within unit (0/1)
    int jq  = w & 3;                    // j-quarter
    int NR1 = u + 1;                    // phase-A rounds (NR1 + NR2 == 33)
    int NR2 = 32 - u;

    const float* Qp = Qg + (size_t)bb * NROW * CK;
    const u16* imgB = ws + (size_t)bb * 32 * TILE_U16;
    const float qscale = 0.125f * 1.44269504088896f;   // 1/sqrt(64)*log2(e)

    bf16x8 qfA[4], qfB[4];              // Q fragments for tiles T0, T1
    auto loadQ = [&](int T, bf16x8* dst) {
        const float* qb = Qp + (size_t)((T << 5) + ql) * CK;
#pragma unroll
        for (int kc = 0; kc < 4; kc++) {
            const float* qp = qb + kc * 16 + hl * 8;
            f32x4 a = *(const f32x4*)qp;
            f32x4 b2 = *(const f32x4*)(qp + 4);
            u32x4 qq;
            qq[0] = cvtpk(a[0] * qscale, a[1] * qscale);
            qq[1] = cvtpk(a[2] * qscale, a[3] * qscale);
            qq[2] = cvtpk(b2[0] * qscale, b2[1] * qscale);
            qq[3] = cvtpk(b2[2] * qscale, b2[3] * qscale);
            dst[kc] = __builtin_bit_cast(bf16x8, qq);
        }
    };
    int T0 = 4 * u + 2 * qs2;           // current phase tile base
    loadQ(T0, qfA);
    loadQ(T0 + 1, qfB);

    f32x16 acc[8];                      // [tile 0/1][4 v-subtiles]
#pragma unroll
    for (int a8 = 0; a8 < 8; a8++)
#pragma unroll
        for (int r = 0; r < 16; r++) acc[a8][r] = 0.f;
    float l0 = 0.f, l1 = 0.f;

    // ---- DMA staging: wave w copies bytes [w*6KB, (w+1)*6KB) of the image ----
    auto issueTile = [&](int img_tile, int buf_u16) {
        const char* src = (const char*)(imgB + (size_t)img_tile * TILE_U16)
                          + w * 6144 + lane * 16;
        char* dst = (char*)smem + (size_t)buf_u16 * 2 + w * 6144;
#pragma unroll
        for (int i = 0; i < 6; i++)
            __builtin_amdgcn_global_load_lds((as1_cvoid*)(src + i * 1024),
                                             (as3_void*)(dst + i * 1024), 16, 0, 0);
    };

    // ---- combine: two passes (tile-slot p), 4-way jq reduction each ----
    auto combine = [&](int Tbase) {
        float* cm = (float*)&smem[2 * TILE_U16];    // [2 qs2][32 q][128 v] f32
        float* lA = cm + 8192;                      // [2][32]
#pragma unroll 1
        for (int p = 0; p < 2; ++p) {
            float lme = p ? l1 : l0;
            float lw = lme + __shfl_xor(lme, 32);
            int Tq = Tbase + p;
            int ab = p * 4;
            if (jq == 0) {
#pragma unroll
                for (int vs = 0; vs < 4; vs++)
#pragma unroll
                    for (int r = 0; r < 16; r++)
                        cm[qs2 * 4096 + crow(r, hl) * 128 + vs * 32 + ql] = acc[ab + vs][r];
                if (lane < 32) lA[qs2 * 32 + lane] = lw;
            }
            __syncthreads();
            if (jq == 1) {
#pragma unroll
                for (int vs = 0; vs < 4; vs++)
#pragma unroll
                    for (int r = 0; r < 16; r++)
                        cm[qs2 * 4096 + crow(r, hl) * 128 + vs * 32 + ql] += acc[ab + vs][r];
                if (lane < 32) lA[qs2 * 32 + lane] += lw;
            }
            __syncthreads();
            if (jq == 2) {
#pragma unroll
                for (int vs = 0; vs < 4; vs++)
#pragma unroll
                    for (int r = 0; r < 16; r++)
                        cm[qs2 * 4096 + crow(r, hl) * 128 + vs * 32 + ql] += acc[ab + vs][r];
                if (lane < 32) lA[qs2 * 32 + lane] += lw;
            }
            __syncthreads();
            if (jq == 3) {
                float ltot = lA[qs2 * 32 + ql] + lw;
                float inv = ((Tq << 5) + ql == 0) ? 0.f : 1.f / ltot;  // row 0 -> 0
                float inv_r[16];
#pragma unroll
                for (int r = 0; r < 16; r++) inv_r[r] = __shfl(inv, crow(r, hl));
                float* Og = O + ((size_t)bb * NROW + ((size_t)Tq << 5)) * CV;
#pragma unroll
                for (int vs = 0; vs < 4; vs++)
#pragma unroll
                    for (int r = 0; r < 16; r++)
                        Og[(size_t)crow(r, hl) * CV + vs * 32 + ql] =
                            (cm[qs2 * 4096 + crow(r, hl) * 128 + vs * 32 + ql] + acc[ab + vs][r]) * inv_r[r];
            }
            __syncthreads();
        }
    };

    issueTile(0, 0);                    // prologue: tile 0 -> buf 0

    for (int rr = 0; rr < 33; ++rr) {
        int cur = (rr & 1) * TILE_U16;
        int nxt = ((rr + 1) & 1) * TILE_U16;

        {   // issue next round's tile: its 6 DMAs stay in flight across barriers
            int nr = rr + 1;
            int jb = (nr < NR1) ? nr : (nr - NR1 < NR2 ? nr - NR1 : NR2 - 1);
            issueTile(jb, nxt);
        }
        // per-wave: wait ONLY for tile rr's 6 DMAs (oldest); keep 6 in flight.
        asm volatile("s_waitcnt vmcnt(6)" ::: "memory");
        __builtin_amdgcn_sched_barrier(0);
        __builtin_amdgcn_s_barrier();      // raw: no compiler vmcnt(0) drain

        if (rr == NR1) {                // phase A done: combine + switch unit
            combine(T0);                // (full drains inside - 1x per kernel)
#pragma unroll
            for (int a8 = 0; a8 < 8; a8++)
#pragma unroll
                for (int r = 0; r < 16; r++) acc[a8][r] = 0.f;
            l0 = 0.f; l1 = 0.f;
            T0 = 4 * (31 - u) + 2 * qs2;
            loadQ(T0, qfA);
            loadQ(T0 + 1, qfB);
        }

        int tt = (rr < NR1) ? rr : rr - NR1;
        int jS = 4 * tt + jq;
        if (jS <= T0 + 1) {             // at least tile1 active
            // ---- shared K and V fragments (12 ds_read_b128, feed 24 MFMAs) ----
            bf16x8 kf0 = *(const bf16x8*)&smem[cur + (SWK(jq * 32 + ql, 0 * 32 + hl * 16) >> 1)];
            bf16x8 kf1 = *(const bf16x8*)&smem[cur + (SWK(jq * 32 + ql, 1 * 32 + hl * 16) >> 1)];
            bf16x8 kf2 = *(const bf16x8*)&smem[cur + (SWK(jq * 32 + ql, 2 * 32 + hl * 16) >> 1)];
            bf16x8 kf3 = *(const bf16x8*)&smem[cur + (SWK(jq * 32 + ql, 3 * 32 + hl * 16) >> 1)];
            bf16x8 vf0[4], vf1[4];
#pragma unroll
            for (int vs = 0; vs < 4; vs++) {
                vf0[vs] = *(const bf16x8*)&smem[cur + 8192 + (SWV(vs * 32 + ql, jq * 64 + hl * 16) >> 1)];
                vf1[vs] = *(const bf16x8*)&smem[cur + 8192 + (SWV(vs * 32 + ql, jq * 64 + 32 + hl * 16) >> 1)];
            }
            __builtin_amdgcn_s_setprio(1);

            // ================= tile 1 (T0+1): always active here =============
            {
                f32x16 S;
#pragma unroll
                for (int r = 0; r < 16; r++) S[r] = 0.f;
                S = __builtin_amdgcn_mfma_f32_32x32x16_bf16(kf0, qfB[0], S, 0, 0, 0);
                S = __builtin_amdgcn_mfma_f32_32x32x16_bf16(kf1, qfB[1], S, 0, 0, 0);
                S = __builtin_amdgcn_mfma_f32_32x32x16_bf16(kf2, qfB[2], S, 0, 0, 0);
                S = __builtin_amdgcn_mfma_f32_32x32x16_bf16(kf3, qfB[3], S, 0, 0, 0);
                float P[16];
                if (jS == T0 + 1) {     // wave-uniform diagonal branch
#pragma unroll
                    for (int r = 0; r < 16; r++) {
                        float pr2 = __builtin_exp2f(S[r]);
                        P[r] = (crow(r, hl) >= ql) ? 0.f : pr2;
                    }
                } else {
#pragma unroll
                    for (int r = 0; r < 16; r++) P[r] = __builtin_exp2f(S[r]);
                }
                {
                    float s0 = (P[0] + P[1]) + (P[2] + P[3]);
                    float s1 = (P[4] + P[5]) + (P[6] + P[7]);
                    float s2 = (P[8] + P[9]) + (P[10] + P[11]);
                    float s3 = (P[12] + P[13]) + (P[14] + P[15]);
                    l1 += (s0 + s1) + (s2 + s3);
                }
                u32 A0 = cvtpk(P[0], P[1]),   B0 = cvtpk(P[2], P[3]);
                u32 A1 = cvtpk(P[4], P[5]),   B1 = cvtpk(P[6], P[7]);
                u32 A2 = cvtpk(P[8], P[9]),   B2 = cvtpk(P[10], P[11]);
                u32 A3 = cvtpk(P[12], P[13]), B3 = cvtpk(P[14], P[15]);
                u32 s1 = hl ? A0 : A1, s2 = hl ? B0 : B1;
                u32 s3 = hl ? A2 : A3, s4 = hl ? B2 : B3;
                u32 r1 = (u32)__shfl_xor((int)s1, 32);
                u32 r2 = (u32)__shfl_xor((int)s2, 32);
                u32 r3 = (u32)__shfl_xor((int)s3, 32);
                u32 r4 = (u32)__shfl_xor((int)s4, 32);
                u32x4 w0, w1;
                w0[0] = hl ? r1 : A0; w0[1] = hl ? r2 : B0;
                w0[2] = hl ? A1 : r1; w0[3] = hl ? B1 : r2;
                w1[0] = hl ? r3 : A2; w1[1] = hl ? r4 : B2;
                w1[2] = hl ? A3 : r3; w1[3] = hl ? B3 : r4;
                bf16x8 pa0 = __builtin_bit_cast(bf16x8, w0);
                bf16x8 pa1 = __builtin_bit_cast(bf16x8, w1);
#pragma unroll
                for (int vs = 0; vs < 4; vs++)
                    acc[4 + vs] = __builtin_amdgcn_mfma_f32_32x32x16_bf16(pa0, vf0[vs], acc[4 + vs], 0, 0, 0);
#pragma unroll
                for (int vs = 0; vs < 4; vs++)
                    acc[4 + vs] = __builtin_amdgcn_mfma_f32_32x32x16_bf16(pa1, vf1[vs], acc[4 + vs], 0, 0, 0);
            }

            // ================= tile 0 (T0): active while jS <= T0 ============
            if (jS <= T0) {
                f32x16 S;
#pragma unroll
                for (int r = 0; r < 16; r++) S[r] = 0.f;
                S = __builtin_amdgcn_mfma_f32_32x32x16_bf16(kf0, qfA[0], S, 0, 0, 0);
                S = __builtin_amdgcn_mfma_f32_32x32x16_bf16(kf1, qfA[1], S, 0, 0, 0);
                S = __builtin_amdgcn_mfma_f32_32x32x16_bf16(kf2, qfA[2], S, 0, 0, 0);
                S = __builtin_amdgcn_mfma_f32_32x32x16_bf16(kf3, qfA[3], S, 0, 0, 0);
                float P[16];
                if (jS == T0) {
#pragma unroll
                    for (int r = 0; r < 16; r++) {
                        float pr2 = __builtin_exp2f(S[r]);
                        P[r] = (crow(r, hl) >= ql) ? 0.f : pr2;
                    }
                } else {
#pragma unroll
                    for (int r = 0; r < 16; r++) P[r] = __builtin_exp2f(S[r]);
                }
                {
                    float s0 = (P[0] + P[1]) + (P[2] + P[3]);
                    float s1 = (P[4] + P[5]) + (P[6] + P[7]);
                    float s2 = (P[8] + P[9]) + (P[10] + P[11]);
                    float s3 = (P[12] + P[13]) + (P[14] + P[15]);
                    l0 += (s0 + s1) + (s2 + s3);
                }
                u32 A0 = cvtpk(P[0], P[1]),   B0 = cvtpk(P[2], P[3]);
                u32 A1 = cvtpk(P[4], P[5]),   B1 = cvtpk(P[6], P[7]);
                u32 A2 = cvtpk(P[8], P[9]),   B2 = cvtpk(P[10], P[11]);
                u32 A3 = cvtpk(P[12], P[13]), B3 = cvtpk(P[14], P[15]);
                u32 s1 = hl ? A0 : A1, s2 = hl ? B0 : B1;
                u32 s3 = hl ? A2 : A3, s4 = hl ? B2 : B3;
                u32 r1 = (u32)__shfl_xor((int)s1, 32);
                u32 r2 = (u32)__shfl_xor((int)s2, 32);
                u32 r3 = (u32)__shfl_xor((int)s3, 32);
                u32 r4 = (u32)__shfl_xor((int)s4, 32);
                u32x4 w0, w1;
                w0[0] = hl ? r1 : A0; w0[1] = hl ? r2 : B0;
                w0[2] = hl ? A1 : r1; w0[3] = hl ? B1 : r2;
                w1[0] = hl ? r3 : A2; w1[1] = hl ? r4 : B2;
                w1[2] = hl ? A3 : r3; w1[3] = hl ? B3 : r4;
                bf16x8 pa0 = __builtin_bit_cast(bf16x8, w0);
                bf16x8 pa1 = __builtin_bit_cast(bf16x8, w1);
#pragma unroll
                for (int vs = 0; vs < 4; vs++)
                    acc[vs] = __builtin_amdgcn_mfma_f32_32x32x16_bf16(pa0, vf0[vs], acc[vs], 0, 0, 0);
#pragma unroll
                for (int vs = 0; vs < 4; vs++)
                    acc[vs] = __builtin_amdgcn_mfma_f32_32x32x16_bf16(pa1, vf1[vs], acc[vs], 0, 0, 0);
            }
            __builtin_amdgcn_s_setprio(0);
        }
        // trailing barrier: all reads of buf[cur] done before it becomes the
        // next round's DMA destination (raw: in-flight DMAs target buf[nxt]).
        __builtin_amdgcn_s_barrier();
    }

    combine(T0);            // phase-B combine + store (drains everything)
}

// ===========================================================================
// Fallback (ws too small): round-8 kernel verbatim (proven 84us).
// ===========================================================================
#define FBUF 24576
#define FVT 8192
__global__ __launch_bounds__(512, 2) void attn_fb(const float* __restrict__ Qg,
                                                  const float* __restrict__ Kg,
                                                  const float* __restrict__ Vg,
                                                  float* __restrict__ O) {
    __shared__ __align__(16) u16 smem[2 * FBUF];
    int bid = blockIdx.x;
    int bb = bid & 7;
    int u  = bid >> 3;
    int t  = threadIdx.x;
    int w  = t >> 6;
    int lane = t & 63;
    int ql = lane & 31, hl = lane >> 5;
    int qsub = w >> 2, jq = w & 3;
    int uL = u, uH = 63 - u;
    int rA = ((2 * uL + 1) >> 2) + 1;
    const float* Qp = Qg + (size_t)bb * NROW * CK;
    const float* Kp = Kg + (size_t)bb * NROW * CK;
    const float* Vp = Vg + (size_t)bb * NROW * CV;
    const float qscale = 0.125f * 1.44269504088896f;
    bf16x8 qf[4];
    auto loadQ = [&](int T) {
        const float* qb = Qp + (size_t)((T << 5) + ql) * CK;
#pragma unroll
        for (int kc = 0; kc < 4; kc++) {
            const float* qp = qb + kc * 16 + hl * 8;
            f32x4 a = *(const f32x4*)qp;
            f32x4 b2 = *(const f32x4*)(qp + 4);
            u32x4 qq;
            qq[0] = cvtpk(a[0] * qscale, a[1] * qscale);
            qq[1] = cvtpk(a[2] * qscale, a[3] * qscale);
            qq[2] = cvtpk(b2[0] * qscale, b2[1] * qscale);
            qq[3] = cvtpk(b2[2] * qscale, b2[3] * qscale);
            qf[kc] = __builtin_bit_cast(bf16x8, qq);
        }
    };
    int T_cur = 2 * uL + qsub;
    loadQ(T_cur);
    f32x16 acc[4];
#pragma unroll
    for (int vs = 0; vs < 4; vs++)
#pragma unroll
        for (int r = 0; r < 16; r++) acc[vs][r] = 0.f;
    float l = 0.f;
    int jK = t >> 2, kc4 = t & 3;
    int vg = t & 15, jgrp = t >> 4;
    const float* kSrc = Kp + (size_t)jK * CK + kc4 * 16;
    const float* vSrc = Vp + (size_t)(jgrp * 4) * CV + vg * 8;
    f32x4 kr0, kr1, kr2, kr3, va0, va1, va2, va3, vb0, vb1, vb2, vb3;
    auto prefetch = [&](int jb) {
        const float* kp = kSrc + (size_t)jb * CK;
        kr0 = *(const f32x4*)kp;       kr1 = *(const f32x4*)(kp + 4);
        kr2 = *(const f32x4*)(kp + 8); kr3 = *(const f32x4*)(kp + 12);
        const float* vp = vSrc + (size_t)jb * CV;
        va0 = *(const f32x4*)vp;            vb0 = *(const f32x4*)(vp + 4);
        va1 = *(const f32x4*)(vp + CV);     vb1 = *(const f32x4*)(vp + CV + 4);
        va2 = *(const f32x4*)(vp + 2 * CV); vb2 = *(const f32x4*)(vp + 2 * CV + 4);
        va3 = *(const f32x4*)(vp + 3 * CV); vb3 = *(const f32x4*)(vp + 3 * CV + 4);
    };
    auto store_tile = [&](int bufo) {
        u32x4 kk0, kk1;
        kk0[0] = cvtpk(kr0[0], kr0[1]); kk0[1] = cvtpk(kr0[2], kr0[3]);
        kk0[2] = cvtpk(kr1[0], kr1[1]); kk0[3] = cvtpk(kr1[2], kr1[3]);
        kk1[0] = cvtpk(kr2[0], kr2[1]); kk1[1] = cvtpk(kr2[2], kr2[3]);
        kk1[2] = cvtpk(kr3[0], kr3[1]); kk1[3] = cvtpk(kr3[2], kr3[3]);
        *(u32x4*)&smem[bufo + (SWK(jK, kc4 * 32) >> 1)]      = kk0;
        *(u32x4*)&smem[bufo + (SWK(jK, kc4 * 32 + 16) >> 1)] = kk1;
#pragma unroll
        for (int x = 0; x < 4; x++) {
            int v = vg * 8 + x;
            u32x2 vv; vv[0] = cvtpk(va0[x], va1[x]); vv[1] = cvtpk(va2[x], va3[x]);
            *(u32x2*)&smem[bufo + FVT + (SWV(v, jgrp * 8) >> 1)] = vv;
        }
#pragma unroll
        for (int x = 0; x < 4; x++) {
            int v = vg * 8 + 4 + x;
            u32x2 vv; vv[0] = cvtpk(vb0[x], vb1[x]); vv[1] = cvtpk(vb2[x], vb3[x]);
            *(u32x2*)&smem[bufo + FVT + (SWV(v, jgrp * 8) >> 1)] = vv;
        }
    };
    auto combine = [&](int scratch, int Tq) {
        float* cm = (float*)(smem + scratch);
        float* lA = cm + 8192;
        float lw = l + __shfl_xor(l, 32);
        if (jq == 0) {
#pragma unroll
            for (int vs = 0; vs < 4; vs++)
#pragma unroll
                for (int r = 0; r < 16; r++)
                    cm[qsub * 4096 + crow(r, hl) * 128 + vs * 32 + ql] = acc[vs][r];
            if (lane < 32) lA[qsub * 32 + lane] = lw;
        }
        __syncthreads();
        if (jq == 1) {
#pragma unroll
            for (int vs = 0; vs < 4; vs++)
#pragma unroll
                for (int r = 0; r < 16; r++)
                    cm[qsub * 4096 + crow(r, hl) * 128 + vs * 32 + ql] += acc[vs][r];
            if (lane < 32) lA[qsub * 32 + lane] += lw;
        }
        __syncthreads();
        if (jq == 2) {
#pragma unroll
            for (int vs = 0; vs < 4; vs++)
#pragma unroll
                for (int r = 0; r < 16; r++)
                    cm[qsub * 4096 + crow(r, hl) * 128 + vs * 32 + ql] += acc[vs][r];
            if (lane < 32) lA[qsub * 32 + lane] += lw;
        }
        __syncthreads();
        if (jq == 3) {
            float ltot = lA[qsub * 32 + ql] + lw;
            float inv = ((Tq << 5) + ql == 0) ? 0.f : 1.f / ltot;
            float inv_r[16];
#pragma unroll
            for (int r = 0; r < 16; r++) inv_r[r] = __shfl(inv, crow(r, hl));
            float* Og = O + ((size_t)bb * NROW + ((size_t)Tq << 5)) * CV;
#pragma unroll
            for (int vs = 0; vs < 4; vs++)
#pragma unroll
                for (int r = 0; r < 16; r++)
                    Og[(size_t)crow(r, hl) * CV + vs * 32 + ql] =
                        (cm[qsub * 4096 + crow(r, hl) * 128 + vs * 32 + ql] + acc[vs][r]) * inv_r[r];
        }
        __syncthreads();
    };
    prefetch(0);
    for (int rr = 0; rr < 33; ++rr) {
        int bufo = (rr & 1) * FBUF;
        store_tile(bufo);
        __syncthreads();
        if (rr == rA) {
            combine(((rA - 1) & 1) * FBUF, T_cur);
#pragma unroll
            for (int vs = 0; vs < 4; vs++)
#pragma unroll
                for (int r = 0; r < 16; r++) acc[vs][r] = 0.f;
            l = 0.f;
            T_cur = 2 * uH + qsub;
            loadQ(T_cur);
        }
        int tt = (rr < rA) ? rr : rr - rA;
        int jS = 4 * tt + jq;
        {
            int nr = rr + 1;
            int jb = (nr < rA) ? (nr << 7)
                               : ((nr <= 32 ? (nr - rA) : (32 - rA)) << 7);
            prefetch(jb);
        }
        if (jS > T_cur) continue;
        bf16x8 kf0 = *(const bf16x8*)&smem[bufo + (SWK(jq * 32 + ql, 0 * 32 + hl * 16) >> 1)];
        bf16x8 kf1 = *(const bf16x8*)&smem[bufo + (SWK(jq * 32 + ql, 1 * 32 + hl * 16) >> 1)];
        bf16x8 kf2 = *(const bf16x8*)&smem[bufo + (SWK(jq * 32 + ql, 2 * 32 + hl * 16) >> 1)];
        bf16x8 kf3 = *(const bf16x8*)&smem[bufo + (SWK(jq * 32 + ql, 3 * 32 + hl * 16) >> 1)];
        f32x16 S;
#pragma unroll
        for (int r = 0; r < 16; r++) S[r] = 0.f;
        __builtin_amdgcn_s_setprio(1);
        S = __builtin_amdgcn_mfma_f32_32x32x16_bf16(kf0, qf[0], S, 0, 0, 0);
        S = __builtin_amdgcn_mfma_f32_32x32x16_bf16(kf1, qf[1], S, 0, 0, 0);
        S = __builtin_amdgcn_mfma_f32_32x32x16_bf16(kf2, qf[2], S, 0, 0, 0);
        S = __builtin_amdgcn_mfma_f32_32x32x16_bf16(kf3, qf[3], S, 0, 0, 0);
        __builtin_amdgcn_s_setprio(0);
        float P[16];
        bool diag = (jS == T_cur);
#pragma unroll
        for (int r = 0; r < 16; r++) {
            float pr2 = __builtin_exp2f(S[r]);
            if (diag) pr2 = (crow(r, hl) >= ql) ? 0.f : pr2;
            P[r] = pr2;
        }
        {
            float s0 = (P[0] + P[1]) + (P[2] + P[3]);
            float s1 = (P[4] + P[5]) + (P[6] + P[7]);
            float s2 = (P[8] + P[9]) + (P[10] + P[11]);
            float s3 = (P[12] + P[13]) + (P[14] + P[15]);
            l += (s0 + s1) + (s2 + s3);
        }
        u32 A0 = cvtpk(P[0], P[1]),   B0 = cvtpk(P[2], P[3]);
        u32 A1 = cvtpk(P[4], P[5]),   B1 = cvtpk(P[6], P[7]);
        u32 A2 = cvtpk(P[8], P[9]),   B2 = cvtpk(P[10], P[11]);
        u32 A3 = cvtpk(P[12], P[13]), B3 = cvtpk(P[14], P[15]);
        u32 s1 = hl ? A0 : A1, s2 = hl ? B0 : B1;
        u32 s3 = hl ? A2 : A3, s4 = hl ? B2 : B3;
        u32 r1 = (u32)__shfl_xor((int)s1, 32);
        u32 r2 = (u32)__shfl_xor((int)s2, 32);
        u32 r3 = (u32)__shfl_xor((int)s3, 32);
        u32 r4 = (u32)__shfl_xor((int)s4, 32);
        bf16x8 vf0[4], vf1[4];
#pragma unroll
        for (int vs = 0; vs < 4; vs++) {
            vf0[vs] = *(const bf16x8*)&smem[bufo + FVT + (SWV(vs * 32 + ql, jq * 64 + hl * 16) >> 1)];
            vf1[vs] = *(const bf16x8*)&smem[bufo + FVT + (SWV(vs * 32 + ql, jq * 64 + 32 + hl * 16) >> 1)];
        }
        u32x4 w0, w1;
        w0[0] = hl ? r1 : A0; w0[1] = hl ? r2 : B0;
        w0[2] = hl ? A1 : r1; w0[3] = hl ? B1 : r2;
        w1[0] = hl ? r3 : A2; w1[1] = hl ? r4 : B2;
        w1[2] = hl ? A3 : r3; w1[3] = hl ? B3 : r4;
        bf16x8 pa0 = __builtin_bit_cast(bf16x8, w0);
        bf16x8 pa1 = __builtin_bit_cast(bf16x8, w1);
        __builtin_amdgcn_s_setprio(1);
#pragma unroll
        for (int vs = 0; vs < 4; vs++)
            acc[vs] = __builtin_amdgcn_mfma_f32_32x32x16_bf16(pa0, vf0[vs], acc[vs], 0, 0, 0);
#pragma unroll
        for (int vs = 0; vs < 4; vs++)
            acc[vs] = __builtin_amdgcn_mfma_f32_32x32x16_bf16(pa1, vf1[vs], acc[vs], 0, 0, 0);
        __builtin_amdgcn_s_setprio(0);
    }
    __syncthreads();
    combine(0, T_cur);
}

// ---------------------------------------------------------------------------
extern "C" void kernel_launch(void* const* d_in, const int* in_sizes, int n_in,
                              void* d_out, int out_size, void* d_ws, size_t ws_size,
                              hipStream_t stream) {
    const float* Q = (const float*)d_in[0];
    const float* K = (const float*)d_in[1];
    const float* V = (const float*)d_in[2];
    float* out = (float*)d_out;
    if (ws_size >= (size_t)WS_NEEDED) {
        u16* ws = (u16*)d_ws;
        hipLaunchKernelGGL(prep_k, dim3(256), dim3(512), 0, stream, K, V, ws);
        hipLaunchKernelGGL(attn_m, dim3(256), dim3(512), 0, stream, Q, ws, out);
    } else {
        hipLaunchKernelGGL(attn_fb, dim3(256), dim3(512), 0, stream, Q, K, V, out);
    }
}

// Round 21
// 76.394 us; speedup vs baseline: 8.8519x; 8.8519x over previous
//
#include <hip/hip_runtime.h>
#include <hip/hip_bf16.h>

typedef unsigned short u16;
typedef unsigned int u32;
typedef __attribute__((ext_vector_type(2))) unsigned int u32x2;
typedef __attribute__((ext_vector_type(4))) unsigned int u32x4;
typedef __attribute__((ext_vector_type(4))) float f32x4;
typedef __attribute__((ext_vector_type(8))) short bf16x8;    // 8 bf16 (4 VGPRs)
typedef __attribute__((ext_vector_type(16))) float f32x16;   // 32x32 MFMA C/D

typedef __attribute__((address_space(1))) const void as1_cvoid;
typedef __attribute__((address_space(3))) void as3_void;

__device__ __forceinline__ u32 cvtpk(float lo, float hi) {   // v_cvt_pk_bf16_f32
    __hip_bfloat162 h = __float22bfloat162_rn(make_float2(lo, hi));
    u32 r; __builtin_memcpy(&r, &h, 4);
    return r;
}
__device__ __forceinline__ int crow(int r, int hl) { return (r & 3) + 8 * (r >> 2) + 4 * hl; }

#define NROW 4096
#define CK 64
#define CV 128
#define TILE_U16 24576          // one 128-row tile image: K 16KB + V^T 32KB = 48KB
#define WS_NEEDED (8u * 32u * 49152u)   // 12,582,912 B
// K tile [128 j][64 c] bf16, 128B rows:
#define SWK(R, o) ((((R) << 7) + (o)) ^ (((R) & 7) << 4))
// V^T tile [128 v][128 j] bf16, 256B rows:
#define SWVG(R) ((((R) >> 3) & 15) ^ (((R) & 7) << 1))
#define SWV(R, o) ((((R) << 8) + (o)) ^ (SWVG(R) << 4))

// ===========================================================================
// Prepass: per-(batch,tile) 48KB LDS images in d_ws (K swizzled + V^T swizzled);
// linear DMA of an image reproduces the exact swizzled LDS layout (m173).
// ===========================================================================
__global__ __launch_bounds__(512, 2) void prep_k(const float* __restrict__ Kg,
                                                 const float* __restrict__ Vg,
                                                 u16* __restrict__ ws) {
    int bid = blockIdx.x;
    int b = bid >> 5, jt = bid & 31;
    int t = threadIdx.x;
    int jK = t >> 2, kc4 = t & 3;
    int vg = t & 15, jgrp = t >> 4;
    const float* Kp = Kg + ((size_t)b * NROW + jt * 128) * CK;
    const float* Vp = Vg + ((size_t)b * NROW + jt * 128) * CV;
    u16* img = ws + (size_t)(b * 32 + jt) * TILE_U16;

    {   // K part
        const float* kp = Kp + (size_t)jK * CK + kc4 * 16;
        f32x4 a0 = *(const f32x4*)kp,       a1 = *(const f32x4*)(kp + 4);
        f32x4 a2 = *(const f32x4*)(kp + 8), a3 = *(const f32x4*)(kp + 12);
        u32x4 kk0, kk1;
        kk0[0] = cvtpk(a0[0], a0[1]); kk0[1] = cvtpk(a0[2], a0[3]);
        kk0[2] = cvtpk(a1[0], a1[1]); kk0[3] = cvtpk(a1[2], a1[3]);
        kk1[0] = cvtpk(a2[0], a2[1]); kk1[1] = cvtpk(a2[2], a2[3]);
        kk1[2] = cvtpk(a3[0], a3[1]); kk1[3] = cvtpk(a3[2], a3[3]);
        *(u32x4*)&img[SWK(jK, kc4 * 32) >> 1]      = kk0;
        *(u32x4*)&img[SWK(jK, kc4 * 32 + 16) >> 1] = kk1;
    }
    {   // V part (transpose 4 j-rows x 8 v-cols)
        const float* vp = Vp + (size_t)(jgrp * 4) * CV + vg * 8;
        f32x4 va0 = *(const f32x4*)vp,            vb0 = *(const f32x4*)(vp + 4);
        f32x4 va1 = *(const f32x4*)(vp + CV),     vb1 = *(const f32x4*)(vp + CV + 4);
        f32x4 va2 = *(const f32x4*)(vp + 2 * CV), vb2 = *(const f32x4*)(vp + 2 * CV + 4);
        f32x4 va3 = *(const f32x4*)(vp + 3 * CV), vb3 = *(const f32x4*)(vp + 3 * CV + 4);
#pragma unroll
        for (int x = 0; x < 4; x++) {
            u32x2 vv;
            vv[0] = cvtpk(va0[x], va1[x]); vv[1] = cvtpk(va2[x], va3[x]);
            *(u32x2*)&img[8192 + (SWV(vg * 8 + x, jgrp * 8) >> 1)] = vv;
            vv[0] = cvtpk(vb0[x], vb1[x]); vv[1] = cvtpk(vb2[x], vb3[x]);
            *(u32x2*)&img[8192 + (SWV(vg * 8 + 4 + x, jgrp * 8) >> 1)] = vv;
        }
    }
}

// ===========================================================================
// Main: 256 blocks x 512 thr (8 waves), 1 block/CU. 33 equal rounds/block.
// Best-measured structure (76.6us total): DMA double buffer from pre-swizzled
// ws images, counted s_waitcnt vmcnt(6) + raw s_barrier, wave-uniform causal
// mask branch, phase-B Q preloaded. VGPR 116 (under the 128 hard cap).
// ===========================================================================
__global__ __launch_bounds__(512, 1) void attn_m(const float* __restrict__ Qg,
                                                 const u16* __restrict__ ws,
                                                 float* __restrict__ O) {
    __shared__ __align__(16) u16 smem[2 * TILE_U16 + 16512];

    int bid = blockIdx.x;
    int bb = bid & 7;
    int u  = bid >> 3;                  // 0..31
    int t  = threadIdx.x;
    int w  = t >> 6;
    int lane = t & 63;
    int ql = lane & 31, hl = lane >> 5;
    int qsub = w >> 2;                  // q-tile within unit
    int jq   = w & 3;                   // j-quarter
    int uL = u, uH = 63 - u;
    int NR1 = ((2 * uL + 1) >> 2) + 1;  // light rounds (NR1 + NR2 == 33)
    int NR2 = 33 - NR1;

    const float* Qp = Qg + (size_t)bb * NROW * CK;
    const u16* imgB = ws + (size_t)bb * 32 * TILE_U16;
    const float qscale = 0.125f * 1.44269504088896f;   // 1/sqrt(64)*log2(e)

    bf16x8 qf[4], qfB[4];
    auto loadQ = [&](int T, bf16x8* dst) {
        const float* qb = Qp + (size_t)((T << 5) + ql) * CK;
#pragma unroll
        for (int kc = 0; kc < 4; kc++) {
            const float* qp = qb + kc * 16 + hl * 8;
            f32x4 a = *(const f32x4*)qp;
            f32x4 b2 = *(const f32x4*)(qp + 4);
            u32x4 qq;
            qq[0] = cvtpk(a[0] * qscale, a[1] * qscale);
            qq[1] = cvtpk(a[2] * qscale, a[3] * qscale);
            qq[2] = cvtpk(b2[0] * qscale, b2[1] * qscale);
            qq[3] = cvtpk(b2[2] * qscale, b2[3] * qscale);
            dst[kc] = __builtin_bit_cast(bf16x8, qq);
        }
    };
    int T_cur = 2 * uL + qsub;
    loadQ(T_cur, qf);
    loadQ(2 * uH + qsub, qfB);          // phase-B Q preloaded

    f32x16 acc[4];
#pragma unroll
    for (int vs = 0; vs < 4; vs++)
#pragma unroll
        for (int r = 0; r < 16; r++) acc[vs][r] = 0.f;
    float l = 0.f;

    // ---- DMA staging: wave w copies bytes [w*6KB, (w+1)*6KB) of the image ----
    auto issueTile = [&](int img_tile, int buf_u16) {
        const char* src = (const char*)(imgB + (size_t)img_tile * TILE_U16)
                          + w * 6144 + lane * 16;
        char* dst = (char*)smem + (size_t)buf_u16 * 2 + w * 6144;
#pragma unroll
        for (int i = 0; i < 6; i++)
            __builtin_amdgcn_global_load_lds((as1_cvoid*)(src + i * 1024),
                                             (as3_void*)(dst + i * 1024), 16, 0, 0);
    };

    // ---- 4-way j-combine + output, dedicated scratch (never the DMA buffers) --
    auto combine = [&](int Tq) {
        float* cm = (float*)&smem[2 * TILE_U16];    // [2][32 q][128 v] f32
        float* lA = cm + 8192;                      // [2][32]
        float lw = l + __shfl_xor(l, 32);
        if (jq == 0) {
#pragma unroll
            for (int vs = 0; vs < 4; vs++)
#pragma unroll
                for (int r = 0; r < 16; r++)
                    cm[qsub * 4096 + crow(r, hl) * 128 + vs * 32 + ql] = acc[vs][r];
            if (lane < 32) lA[qsub * 32 + lane] = lw;
        }
        __syncthreads();
        if (jq == 1) {
#pragma unroll
            for (int vs = 0; vs < 4; vs++)
#pragma unroll
                for (int r = 0; r < 16; r++)
                    cm[qsub * 4096 + crow(r, hl) * 128 + vs * 32 + ql] += acc[vs][r];
            if (lane < 32) lA[qsub * 32 + lane] += lw;
        }
        __syncthreads();
        if (jq == 2) {
#pragma unroll
            for (int vs = 0; vs < 4; vs++)
#pragma unroll
                for (int r = 0; r < 16; r++)
                    cm[qsub * 4096 + crow(r, hl) * 128 + vs * 32 + ql] += acc[vs][r];
            if (lane < 32) lA[qsub * 32 + lane] += lw;
        }
        __syncthreads();
        if (jq == 3) {
            float ltot = lA[qsub * 32 + ql] + lw;
            float inv = ((Tq << 5) + ql == 0) ? 0.f : 1.f / ltot;  // batch row 0 -> 0
            float inv_r[16];
#pragma unroll
            for (int r = 0; r < 16; r++) inv_r[r] = __shfl(inv, crow(r, hl));
            float* Og = O + ((size_t)bb * NROW + ((size_t)Tq << 5)) * CV;
#pragma unroll
            for (int vs = 0; vs < 4; vs++)
#pragma unroll
                for (int r = 0; r < 16; r++)
                    Og[(size_t)crow(r, hl) * CV + vs * 32 + ql] =
                        (cm[qsub * 4096 + crow(r, hl) * 128 + vs * 32 + ql] + acc[vs][r]) * inv_r[r];
        }
        __syncthreads();
    };

    issueTile(0, 0);                    // prologue: tile 0 -> buf 0

    for (int rr = 0; rr < 33; ++rr) {
        int cur = (rr & 1) * TILE_U16;
        int nxt = ((rr + 1) & 1) * TILE_U16;

        {   // issue next round's tile: its 6 DMAs stay in flight across barriers
            int nr = rr + 1;
            int jb = (nr < NR1) ? nr : (nr - NR1 < NR2 ? nr - NR1 : NR2 - 1);
            issueTile(jb, nxt);
        }
        // per-wave: wait ONLY for tile rr's 6 DMAs (oldest); keep 6 in flight.
        asm volatile("s_waitcnt vmcnt(6)" ::: "memory");
        __builtin_amdgcn_sched_barrier(0);
        __builtin_amdgcn_s_barrier();      // raw: no compiler vmcnt(0) drain

        if (rr == NR1) {                // light unit done: combine + switch
            combine(T_cur);             // (full drains inside - 1x per kernel)
#pragma unroll
            for (int vs = 0; vs < 4; vs++)
#pragma unroll
                for (int r = 0; r < 16; r++) acc[vs][r] = 0.f;
            l = 0.f;
            T_cur = 2 * uH + qsub;
#pragma unroll
            for (int kc = 0; kc < 4; kc++) qf[kc] = qfB[kc];   // preloaded
        }

        int tt = (rr < NR1) ? rr : rr - NR1;
        int jS = 4 * tt + jq;
        if (jS <= T_cur) {
            // ---- K fragments ----
            bf16x8 kf0 = *(const bf16x8*)&smem[cur + (SWK(jq * 32 + ql, 0 * 32 + hl * 16) >> 1)];
            bf16x8 kf1 = *(const bf16x8*)&smem[cur + (SWK(jq * 32 + ql, 1 * 32 + hl * 16) >> 1)];
            bf16x8 kf2 = *(const bf16x8*)&smem[cur + (SWK(jq * 32 + ql, 2 * 32 + hl * 16) >> 1)];
            bf16x8 kf3 = *(const bf16x8*)&smem[cur + (SWK(jq * 32 + ql, 3 * 32 + hl * 16) >> 1)];

            // ---- QK^T swapped (S = K x Q): 2 independent 2-chains ----
            f32x16 Sa, Sb;
#pragma unroll
            for (int r = 0; r < 16; r++) { Sa[r] = 0.f; Sb[r] = 0.f; }
            __builtin_amdgcn_s_setprio(1);
            Sa = __builtin_amdgcn_mfma_f32_32x32x16_bf16(kf0, qf[0], Sa, 0, 0, 0);
            Sb = __builtin_amdgcn_mfma_f32_32x32x16_bf16(kf2, qf[2], Sb, 0, 0, 0);
            Sa = __builtin_amdgcn_mfma_f32_32x32x16_bf16(kf1, qf[1], Sa, 0, 0, 0);
            Sb = __builtin_amdgcn_mfma_f32_32x32x16_bf16(kf3, qf[3], Sb, 0, 0, 0);
            __builtin_amdgcn_s_setprio(0);

            // ---- P = exp2(S); mask only on the (wave-uniform) diagonal slice ----
            float P[16];
            if (jS == T_cur) {          // wave-uniform -> s_cbranch, not predication
#pragma unroll
                for (int r = 0; r < 16; r++) {
                    float pr2 = __builtin_exp2f(Sa[r] + Sb[r]);
                    P[r] = (crow(r, hl) >= ql) ? 0.f : pr2;
                }
            } else {
#pragma unroll
                for (int r = 0; r < 16; r++)
                    P[r] = __builtin_exp2f(Sa[r] + Sb[r]);
            }
            {
                float s0 = (P[0] + P[1]) + (P[2] + P[3]);
                float s1 = (P[4] + P[5]) + (P[6] + P[7]);
                float s2 = (P[8] + P[9]) + (P[10] + P[11]);
                float s3 = (P[12] + P[13]) + (P[14] + P[15]);
                l += (s0 + s1) + (s2 + s3);
            }

            // ---- P -> A-fragments: cvt_pk + batched shfl + selects ----
            u32 A0 = cvtpk(P[0], P[1]),   B0 = cvtpk(P[2], P[3]);
            u32 A1 = cvtpk(P[4], P[5]),   B1 = cvtpk(P[6], P[7]);
            u32 A2 = cvtpk(P[8], P[9]),   B2 = cvtpk(P[10], P[11]);
            u32 A3 = cvtpk(P[12], P[13]), B3 = cvtpk(P[14], P[15]);
            u32 s1 = hl ? A0 : A1, s2 = hl ? B0 : B1;
            u32 s3 = hl ? A2 : A3, s4 = hl ? B2 : B3;
            u32 r1 = (u32)__shfl_xor((int)s1, 32);
            u32 r2 = (u32)__shfl_xor((int)s2, 32);
            u32 r3 = (u32)__shfl_xor((int)s3, 32);
            u32 r4 = (u32)__shfl_xor((int)s4, 32);

            bf16x8 vf0[4], vf1[4];      // issued while shfls are in flight
#pragma unroll
            for (int vs = 0; vs < 4; vs++) {
                vf0[vs] = *(const bf16x8*)&smem[cur + 8192 + (SWV(vs * 32 + ql, jq * 64 + hl * 16) >> 1)];
                vf1[vs] = *(const bf16x8*)&smem[cur + 8192 + (SWV(vs * 32 + ql, jq * 64 + 32 + hl * 16) >> 1)];
            }
            u32x4 w0, w1;
            w0[0] = hl ? r1 : A0; w0[1] = hl ? r2 : B0;
            w0[2] = hl ? A1 : r1; w0[3] = hl ? B1 : r2;
            w1[0] = hl ? r3 : A2; w1[1] = hl ? r4 : B2;
            w1[2] = hl ? A3 : r3; w1[3] = hl ? B3 : r4;
            bf16x8 pa0 = __builtin_bit_cast(bf16x8, w0);
            bf16x8 pa1 = __builtin_bit_cast(bf16x8, w1);

            // ---- PV: 4 independent chains of 2 ----
            __builtin_amdgcn_s_setprio(1);
#pragma unroll
            for (int vs = 0; vs < 4; vs++)
                acc[vs] = __builtin_amdgcn_mfma_f32_32x32x16_bf16(pa0, vf0[vs], acc[vs], 0, 0, 0);
#pragma unroll
            for (int vs = 0; vs < 4; vs++)
                acc[vs] = __builtin_amdgcn_mfma_f32_32x32x16_bf16(pa1, vf1[vs], acc[vs], 0, 0, 0);
            __builtin_amdgcn_s_setprio(0);
        }
        // trailing barrier: all reads of buf[cur] done before it becomes the
        // next round's DMA destination (raw: in-flight DMAs target buf[nxt]).
        __builtin_amdgcn_s_barrier();
    }

    combine(T_cur);         // heavy-phase combine + store (drains everything)
}

// ===========================================================================
// Fallback (ws too small): round-8 kernel verbatim (proven 84us).
// ===========================================================================
#define FBUF 24576
#define FVT 8192
__global__ __launch_bounds__(512, 2) void attn_fb(const float* __restrict__ Qg,
                                                  const float* __restrict__ Kg,
                                                  const float* __restrict__ Vg,
                                                  float* __restrict__ O) {
    __shared__ __align__(16) u16 smem[2 * FBUF];
    int bid = blockIdx.x;
    int bb = bid & 7;
    int u  = bid >> 3;
    int t  = threadIdx.x;
    int w  = t >> 6;
    int lane = t & 63;
    int ql = lane & 31, hl = lane >> 5;
    int qsub = w >> 2, jq = w & 3;
    int uL = u, uH = 63 - u;
    int rA = ((2 * uL + 1) >> 2) + 1;
    const float* Qp = Qg + (size_t)bb * NROW * CK;
    const float* Kp = Kg + (size_t)bb * NROW * CK;
    const float* Vp = Vg + (size_t)bb * NROW * CV;
    const float qscale = 0.125f * 1.44269504088896f;
    bf16x8 qf[4];
    auto loadQ = [&](int T) {
        const float* qb = Qp + (size_t)((T << 5) + ql) * CK;
#pragma unroll
        for (int kc = 0; kc < 4; kc++) {
            const float* qp = qb + kc * 16 + hl * 8;
            f32x4 a = *(const f32x4*)qp;
            f32x4 b2 = *(const f32x4*)(qp + 4);
            u32x4 qq;
            qq[0] = cvtpk(a[0] * qscale, a[1] * qscale);
            qq[1] = cvtpk(a[2] * qscale, a[3] * qscale);
            qq[2] = cvtpk(b2[0] * qscale, b2[1] * qscale);
            qq[3] = cvtpk(b2[2] * qscale, b2[3] * qscale);
            qf[kc] = __builtin_bit_cast(bf16x8, qq);
        }
    };
    int T_cur = 2 * uL + qsub;
    loadQ(T_cur);
    f32x16 acc[4];
#pragma unroll
    for (int vs = 0; vs < 4; vs++)
#pragma unroll
        for (int r = 0; r < 16; r++) acc[vs][r] = 0.f;
    float l = 0.f;
    int jK = t >> 2, kc4 = t & 3;
    int vg = t & 15, jgrp = t >> 4;
    const float* kSrc = Kp + (size_t)jK * CK + kc4 * 16;
    const float* vSrc = Vp + (size_t)(jgrp * 4) * CV + vg * 8;
    f32x4 kr0, kr1, kr2, kr3, va0, va1, va2, va3, vb0, vb1, vb2, vb3;
    auto prefetch = [&](int jb) {
        const float* kp = kSrc + (size_t)jb * CK;
        kr0 = *(const f32x4*)kp;       kr1 = *(const f32x4*)(kp + 4);
        kr2 = *(const f32x4*)(kp + 8); kr3 = *(const f32x4*)(kp + 12);
        const float* vp = vSrc + (size_t)jb * CV;
        va0 = *(const f32x4*)vp;            vb0 = *(const f32x4*)(vp + 4);
        va1 = *(const f32x4*)(vp + CV);     vb1 = *(const f32x4*)(vp + CV + 4);
        va2 = *(const f32x4*)(vp + 2 * CV); vb2 = *(const f32x4*)(vp + 2 * CV + 4);
        va3 = *(const f32x4*)(vp + 3 * CV); vb3 = *(const f32x4*)(vp + 3 * CV + 4);
    };
    auto store_tile = [&](int bufo) {
        u32x4 kk0, kk1;
        kk0[0] = cvtpk(kr0[0], kr0[1]); kk0[1] = cvtpk(kr0[2], kr0[3]);
        kk0[2] = cvtpk(kr1[0], kr1[1]); kk0[3] = cvtpk(kr1[2], kr1[3]);
        kk1[0] = cvtpk(kr2[0], kr2[1]); kk1[1] = cvtpk(kr2[2], kr2[3]);
        kk1[2] = cvtpk(kr3[0], kr3[1]); kk1[3] = cvtpk(kr3[2], kr3[3]);
        *(u32x4*)&smem[bufo + (SWK(jK, kc4 * 32) >> 1)]      = kk0;
        *(u32x4*)&smem[bufo + (SWK(jK, kc4 * 32 + 16) >> 1)] = kk1;
#pragma unroll
        for (int x = 0; x < 4; x++) {
            int v = vg * 8 + x;
            u32x2 vv; vv[0] = cvtpk(va0[x], va1[x]); vv[1] = cvtpk(va2[x], va3[x]);
            *(u32x2*)&smem[bufo + FVT + (SWV(v, jgrp * 8) >> 1)] = vv;
        }
#pragma unroll
        for (int x = 0; x < 4; x++) {
            int v = vg * 8 + 4 + x;
            u32x2 vv; vv[0] = cvtpk(vb0[x], vb1[x]); vv[1] = cvtpk(vb2[x], vb3[x]);
            *(u32x2*)&smem[bufo + FVT + (SWV(v, jgrp * 8) >> 1)] = vv;
        }
    };
    auto combine = [&](int scratch, int Tq) {
        float* cm = (float*)(smem + scratch);
        float* lA = cm + 8192;
        float lw = l + __shfl_xor(l, 32);
        if (jq == 0) {
#pragma unroll
            for (int vs = 0; vs < 4; vs++)
#pragma unroll
                for (int r = 0; r < 16; r++)
                    cm[qsub * 4096 + crow(r, hl) * 128 + vs * 32 + ql] = acc[vs][r];
            if (lane < 32) lA[qsub * 32 + lane] = lw;
        }
        __syncthreads();
        if (jq == 1) {
#pragma unroll
            for (int vs = 0; vs < 4; vs++)
#pragma unroll
                for (int r = 0; r < 16; r++)
                    cm[qsub * 4096 + crow(r, hl) * 128 + vs * 32 + ql] += acc[vs][r];
            if (lane < 32) lA[qsub * 32 + lane] += lw;
        }
        __syncthreads();
        if (jq == 2) {
#pragma unroll
            for (int vs = 0; vs < 4; vs++)
#pragma unroll
                for (int r = 0; r < 16; r++)
                    cm[qsub * 4096 + crow(r, hl) * 128 + vs * 32 + ql] += acc[vs][r];
            if (lane < 32) lA[qsub * 32 + lane] += lw;
        }
        __syncthreads();
        if (jq == 3) {
            float ltot = lA[qsub * 32 + ql] + lw;
            float inv = ((Tq << 5) + ql == 0) ? 0.f : 1.f / ltot;
            float inv_r[16];
#pragma unroll
            for (int r = 0; r < 16; r++) inv_r[r] = __shfl(inv, crow(r, hl));
            float* Og = O + ((size_t)bb * NROW + ((size_t)Tq << 5)) * CV;
#pragma unroll
            for (int vs = 0; vs < 4; vs++)
#pragma unroll
                for (int r = 0; r < 16; r++)
                    Og[(size_t)crow(r, hl) * CV + vs * 32 + ql] =
                        (cm[qsub * 4096 + crow(r, hl) * 128 + vs * 32 + ql] + acc[vs][r]) * inv_r[r];
        }
        __syncthreads();
    };
    prefetch(0);
    for (int rr = 0; rr < 33; ++rr) {
        int bufo = (rr & 1) * FBUF;
        store_tile(bufo);
        __syncthreads();
        if (rr == rA) {
            combine(((rA - 1) & 1) * FBUF, T_cur);
#pragma unroll
            for (int vs = 0; vs < 4; vs++)
#pragma unroll
                for (int r = 0; r < 16; r++) acc[vs][r] = 0.f;
            l = 0.f;
            T_cur = 2 * uH + qsub;
            loadQ(T_cur);
        }
        int tt = (rr < rA) ? rr : rr - rA;
        int jS = 4 * tt + jq;
        {
            int nr = rr + 1;
            int jb = (nr < rA) ? (nr << 7)
                               : ((nr <= 32 ? (nr - rA) : (32 - rA)) << 7);
            prefetch(jb);
        }
        if (jS > T_cur) continue;
        bf16x8 kf0 = *(const bf16x8*)&smem[bufo + (SWK(jq * 32 + ql, 0 * 32 + hl * 16) >> 1)];
        bf16x8 kf1 = *(const bf16x8*)&smem[bufo + (SWK(jq * 32 + ql, 1 * 32 + hl * 16) >> 1)];
        bf16x8 kf2 = *(const bf16x8*)&smem[bufo + (SWK(jq * 32 + ql, 2 * 32 + hl * 16) >> 1)];
        bf16x8 kf3 = *(const bf16x8*)&smem[bufo + (SWK(jq * 32 + ql, 3 * 32 + hl * 16) >> 1)];
        f32x16 S;
#pragma unroll
        for (int r = 0; r < 16; r++) S[r] = 0.f;
        __builtin_amdgcn_s_setprio(1);
        S = __builtin_amdgcn_mfma_f32_32x32x16_bf16(kf0, qf[0], S, 0, 0, 0);
        S = __builtin_amdgcn_mfma_f32_32x32x16_bf16(kf1, qf[1], S, 0, 0, 0);
        S = __builtin_amdgcn_mfma_f32_32x32x16_bf16(kf2, qf[2], S, 0, 0, 0);
        S = __builtin_amdgcn_mfma_f32_32x32x16_bf16(kf3, qf[3], S, 0, 0, 0);
        __builtin_amdgcn_s_setprio(0);
        float P[16];
        bool diag = (jS == T_cur);
#pragma unroll
        for (int r = 0; r < 16; r++) {
            float pr2 = __builtin_exp2f(S[r]);
            if (diag) pr2 = (crow(r, hl) >= ql) ? 0.f : pr2;
            P[r] = pr2;
        }
        {
            float s0 = (P[0] + P[1]) + (P[2] + P[3]);
            float s1 = (P[4] + P[5]) + (P[6] + P[7]);
            float s2 = (P[8] + P[9]) + (P[10] + P[11]);
            float s3 = (P[12] + P[13]) + (P[14] + P[15]);
            l += (s0 + s1) + (s2 + s3);
        }
        u32 A0 = cvtpk(P[0], P[1]),   B0 = cvtpk(P[2], P[3]);
        u32 A1 = cvtpk(P[4], P[5]),   B1 = cvtpk(P[6], P[7]);
        u32 A2 = cvtpk(P[8], P[9]),   B2 = cvtpk(P[10], P[11]);
        u32 A3 = cvtpk(P[12], P[13]), B3 = cvtpk(P[14], P[15]);
        u32 s1 = hl ? A0 : A1, s2 = hl ? B0 : B1;
        u32 s3 = hl ? A2 : A3, s4 = hl ? B2 : B3;
        u32 r1 = (u32)__shfl_xor((int)s1, 32);
        u32 r2 = (u32)__shfl_xor((int)s2, 32);
        u32 r3 = (u32)__shfl_xor((int)s3, 32);
        u32 r4 = (u32)__shfl_xor((int)s4, 32);
        bf16x8 vf0[4], vf1[4];
#pragma unroll
        for (int vs = 0; vs < 4; vs++) {
            vf0[vs] = *(const bf16x8*)&smem[bufo + FVT + (SWV(vs * 32 + ql, jq * 64 + hl * 16) >> 1)];
            vf1[vs] = *(const bf16x8*)&smem[bufo + FVT + (SWV(vs * 32 + ql, jq * 64 + 32 + hl * 16) >> 1)];
        }
        u32x4 w0, w1;
        w0[0] = hl ? r1 : A0; w0[1] = hl ? r2 : B0;
        w0[2] = hl ? A1 : r1; w0[3] = hl ? B1 : r2;
        w1[0] = hl ? r3 : A2; w1[1] = hl ? r4 : B2;
        w1[2] = hl ? A3 : r3; w1[3] = hl ? B3 : r4;
        bf16x8 pa0 = __builtin_bit_cast(bf16x8, w0);
        bf16x8 pa1 = __builtin_bit_cast(bf16x8, w1);
        __builtin_amdgcn_s_setprio(1);
#pragma unroll
        for (int vs = 0; vs < 4; vs++)
            acc[vs] = __builtin_amdgcn_mfma_f32_32x32x16_bf16(pa0, vf0[vs], acc[vs], 0, 0, 0);
#pragma unroll
        for (int vs = 0; vs < 4; vs++)
            acc[vs] = __builtin_amdgcn_mfma_f32_32x32x16_bf16(pa1, vf1[vs], acc[vs], 0, 0, 0);
        __builtin_amdgcn_s_setprio(0);
    }
    __syncthreads();
    combine(0, T_cur);
}

// ---------------------------------------------------------------------------
extern "C" void kernel_launch(void* const* d_in, const int* in_sizes, int n_in,
                              void* d_out, int out_size, void* d_ws, size_t ws_size,
                              hipStream_t stream) {
    const float* Q = (const float*)d_in[0];
    const float* K = (const float*)d_in[1];
    const float* V = (const float*)d_in[2];
    float* out = (float*)d_out;
    if (ws_size >= (size_t)WS_NEEDED) {
        u16* ws = (u16*)d_ws;
        hipLaunchKernelGGL(prep_k, dim3(256), dim3(512), 0, stream, K, V, ws);
        hipLaunchKernelGGL(attn_m, dim3(256), dim3(512), 0, stream, Q, ws, out);
    } else {
        hipLaunchKernelGGL(attn_fb, dim3(256), dim3(512), 0, stream, Q, K, V, out);
    }
}